// Round 12
// baseline (196.499 us; speedup 1.0000x reference)
//
#include <hip/hip_runtime.h>
#include <hip/hip_fp16.h>
#include <math.h>

constexpr float NEG_SLOPE = 0.2f;
constexpr int NPART = 8;   // partitions (blockIdx & 7 proxy)
constexpr int WSLOT = 16;  // slots per (node,partition)

// ---------------------------------------------------------------------------
// helpers
// ---------------------------------------------------------------------------
__device__ inline __half2 u2h(unsigned int u) { return *reinterpret_cast<__half2*>(&u); }
__device__ inline unsigned int h2u(__half2 h) { return *reinterpret_cast<unsigned int*>(&h); }

#if __has_builtin(__builtin_amdgcn_readlane)
#define RDLANE(v, l) __builtin_amdgcn_readlane((v), (l))
#else
#define RDLANE(v, l) __shfl((v), (l))
#endif

__device__ inline void fmamix8(uint4 v, float al, float* acc) {
    float2 f0 = __half22float2(u2h(v.x)), f1 = __half22float2(u2h(v.y));
    float2 f2 = __half22float2(u2h(v.z)), f3 = __half22float2(u2h(v.w));
    acc[0] = fmaf(al, f0.x, acc[0]); acc[1] = fmaf(al, f0.y, acc[1]);
    acc[2] = fmaf(al, f1.x, acc[2]); acc[3] = fmaf(al, f1.y, acc[3]);
    acc[4] = fmaf(al, f2.x, acc[4]); acc[5] = fmaf(al, f2.y, acc[5]);
    acc[6] = fmaf(al, f3.x, acc[6]); acc[7] = fmaf(al, f3.y, acc[7]);
}

// resolve virtual list index l (>=1) -> source node id; node-major ELL:
// ell[(node*NPART + p)*WSLOT + slot] -- all partitions of a node in 256 B.
__device__ inline int ell_resolve(const unsigned short* __restrict__ ell,
                                  const int* pre, int node, int l) {
    int p = 0;
#pragma unroll
    for (int t = 1; t < NPART; t++)
        if (l >= pre[t]) p = t;
    int slot = l - pre[p];
    return (int)ell[((size_t)node * NPART + p) * WSLOT + slot];
}

// ---------------------------------------------------------------------------
// W2 transpose: Wt2h[c][k] fp16 from W2[k][c] fp32 (64x128 = 16 KB; built once)
// ---------------------------------------------------------------------------
__global__ void k_wt2(const float* __restrict__ W2, __half* __restrict__ Wt2h) {
    int id = blockIdx.x * 256 + threadIdx.x;
    if (id < 64 * 128) {
        int c = id >> 7, k = id & 127;
        Wt2h[id] = __float2half(W2[k * 64 + c]);
    }
}

// ---------------------------------------------------------------------------
// FUSED: scatter (ELL build) interleaved 1:2 with GEMM1+att1.
// GEMM: W staged in two 64-row fp16 halves -> 32 KB LDS -> 5 blocks/CU.
// ---------------------------------------------------------------------------
__global__ __launch_bounds__(256) void k_fused1(
    const int* __restrict__ src, const int* __restrict__ dst, int e, int S, int G,
    int* __restrict__ cur, unsigned short* __restrict__ ell,
    const float* __restrict__ x, const float* __restrict__ W,
    const float* __restrict__ a_src, const float* __restrict__ a_dst,
    __half* __restrict__ h1h, float* __restrict__ att, int n) {
    __shared__ float xs[32 * 128];    // 16 KB
    __shared__ __half wsh[64 * 128];  // 16 KB (half-K W tile)
    int bid = blockIdx.x;
    int t = threadIdx.x;

    int third = bid / 3;
    bool interleave = (2 * S <= G + 2);
    bool isScat = interleave ? ((bid % 3 == 0) && (third < S)) : (bid < S);
    if (isScat) {
        int sid = interleave ? third : bid;
        int p = bid & (NPART - 1);
        int i0 = (sid * 256 + t) * 4;
        if (i0 + 3 < e) {
            int4 d4 = *reinterpret_cast<const int4*>(dst + i0);
            int4 s4 = *reinterpret_cast<const int4*>(src + i0);
            int a0 = atomicAdd(&cur[d4.x * NPART + p], 1);
            int a1 = atomicAdd(&cur[d4.y * NPART + p], 1);
            int a2 = atomicAdd(&cur[d4.z * NPART + p], 1);
            int a3 = atomicAdd(&cur[d4.w * NPART + p], 1);
            if (a0 < WSLOT) ell[((size_t)d4.x * NPART + p) * WSLOT + a0] = (unsigned short)s4.x;
            if (a1 < WSLOT) ell[((size_t)d4.y * NPART + p) * WSLOT + a1] = (unsigned short)s4.y;
            if (a2 < WSLOT) ell[((size_t)d4.z * NPART + p) * WSLOT + a2] = (unsigned short)s4.z;
            if (a3 < WSLOT) ell[((size_t)d4.w * NPART + p) * WSLOT + a3] = (unsigned short)s4.w;
        } else {
            for (int i = i0; i < e; i++) {
                int d = dst[i];
                int slot = atomicAdd(&cur[d * NPART + p], 1);
                if (slot < WSLOT) ell[((size_t)d * NPART + p) * WSLOT + slot] = (unsigned short)src[i];
            }
        }
        return;
    }
    int gid = interleave ? (bid - min(S, (bid + 2) / 3)) : (bid - S);
    if (gid >= G) return;

    // ---- GEMM1 (32 rows x 128 cols), W fp16 half-K staged ----
    int row0 = gid * 32;
    const float4* xv = (const float4*)x;
    float4* xsv = (float4*)xs;
#pragma unroll
    for (int ii = 0; ii < 4; ii++) {
        int i = t + 256 * ii;
        int r = i >> 5, c4 = i & 31;
        int gr = row0 + r;
        float4 v = (gr < n) ? xv[(size_t)gr * 32 + c4] : make_float4(0.f, 0.f, 0.f, 0.f);
        xsv[i] = v;
    }

    int tc = t & 31;   // cols 4tc..4tc+3
    int tr = t >> 5;   // rows 4tr..4tr+3
    float acc[4][4];
#pragma unroll
    for (int i = 0; i < 4; i++)
#pragma unroll
        for (int j = 0; j < 4; j++) acc[i][j] = 0.f;

    const float4* Wv = (const float4*)W;
    uint2* wsv = (uint2*)wsh;
    const uint2* wsv2 = (const uint2*)wsh;
#pragma unroll
    for (int kh = 0; kh < 2; kh++) {
        __syncthreads();  // first iter: covers x staging; later: wsh reuse
        // stage W rows kh*64..kh*64+63 (fp32 -> fp16)
#pragma unroll
        for (int ii = 0; ii < 8; ii++) {
            int i = t + 256 * ii;  // 0..2047 float4s within this half
            float4 w = Wv[kh * 2048 + i];
            __half2 a = __floats2half2_rn(w.x, w.y);
            __half2 b = __floats2half2_rn(w.z, w.w);
            uint2 o; o.x = h2u(a); o.y = h2u(b);
            wsv[i] = o;
        }
        __syncthreads();
        for (int kk = 0; kk < 64; kk++) {
            uint2 wu = wsv2[kk * 32 + tc];
            float2 wA = __half22float2(u2h(wu.x));
            float2 wB = __half22float2(u2h(wu.y));
#pragma unroll
            for (int i = 0; i < 4; i++) {
                float xvv = xs[(tr * 4 + i) * 128 + kh * 64 + kk];
                acc[i][0] = fmaf(xvv, wA.x, acc[i][0]);
                acc[i][1] = fmaf(xvv, wA.y, acc[i][1]);
                acc[i][2] = fmaf(xvv, wB.x, acc[i][2]);
                acc[i][3] = fmaf(xvv, wB.y, acc[i][3]);
            }
        }
    }

#pragma unroll
    for (int i = 0; i < 4; i++) {
        int gr = row0 + tr * 4 + i;
        if (gr < n) {
            __half2 p01 = __floats2half2_rn(acc[i][0], acc[i][1]);
            __half2 p23 = __floats2half2_rn(acc[i][2], acc[i][3]);
            uint2 o; o.x = h2u(p01); o.y = h2u(p23);
            *reinterpret_cast<uint2*>(h1h + (size_t)gr * 128 + 4 * tc) = o;
        }
    }
    // fused att dots
    const float4* asv = (const float4*)a_src;  // [32] float4 = 128 ch
    const float4* adv = (const float4*)a_dst;
    float4 as4 = asv[tc], ad4 = adv[tc];
    int lane = t & 63;
#pragma unroll
    for (int i = 0; i < 4; i++) {
        float s = acc[i][0] * as4.x + acc[i][1] * as4.y + acc[i][2] * as4.z + acc[i][3] * as4.w;
        float d = acc[i][0] * ad4.x + acc[i][1] * ad4.y + acc[i][2] * ad4.z + acc[i][3] * ad4.w;
#pragma unroll
        for (int o = 1; o < 16; o <<= 1) {
            s += __shfl_xor(s, o);
            d += __shfl_xor(d, o);
        }
        float s1 = __shfl(s, (lane & 32) + 16);
        float d1 = __shfl(d, (lane & 32) + 16);
        int gr = row0 + tr * 4 + i;
        if ((lane & 31) == 0 && gr < n) {
            ((float4*)att)[gr] = make_float4(s, s1, d, d1);
        }
    }
}

// ---------------------------------------------------------------------------
// aggr1 + GEMM2 + att2 fused: one 64-lane wave per dst node.
// Phase 1 (aggr): 2 heads x 64 ch softmax-aggregate (32 edges/iter, MLP=8,
//   fp16 hfma2), xor-reduce -> every lane holds the full 128-ch x2 row.
// Phase 2 (epilogue): bias+ELU in all lanes; lane c computes
//   h2[c] = sum_k x2[k] * W2[k][c] via v_readlane broadcasts + fp16 W2
//   column from cache-hot Wt2h; att2 dots reduced across the wave.
// x2 never touches memory; gemm2 kernel eliminated.
// ---------------------------------------------------------------------------
__global__ __launch_bounds__(256, 4) void k_aggr1g2(
    const int* __restrict__ cur, const unsigned short* __restrict__ ell,
    const float* __restrict__ att, const __half* __restrict__ h1h,
    const float* __restrict__ bias, const __half* __restrict__ Wt2h,
    const float* __restrict__ as2, const float* __restrict__ ad2,
    __half* __restrict__ h2h, float* __restrict__ att2, int n) {
    int wid = threadIdx.x >> 6, lane = threadIdx.x & 63;
    int node = blockIdx.x * 4 + wid;
    if (node >= n) return;

    int cnt = 0;
    if (lane < NPART) cnt = cur[node * NPART + lane];  // coalesced 32 B
    int pre[NPART];
    int tot = 1;  // implicit self-loop at l=0
#pragma unroll
    for (int p = 0; p < NPART; p++) {
        int cc = __shfl(cnt, p);
        cc = cc < WSLOT ? cc : WSLOT;
        pre[p] = tot;
        tot += cc;
    }

    const float4* attv = (const float4*)att;
    float4 an = attv[node];
    float ad0 = an.z, ad1 = an.w;

    int chq = lane & 15;
    int g = lane >> 4;
    bool hsel = (chq >= 8);

    float f[8];

    if (tot <= 64) {
        int c = node;
        float p0 = 0.f, p1 = 0.f;
        if (lane < tot) {
            if (lane > 0) c = ell_resolve(ell, pre, node, lane);
            float4 a = attv[c];
            float e0 = a.x + ad0; e0 = e0 > 0.f ? e0 : NEG_SLOPE * e0;
            float e1 = a.y + ad1; e1 = e1 > 0.f ? e1 : NEG_SLOPE * e1;
            p0 = __expf(e0); p1 = __expf(e1);
        }
        float sum0 = p0, sum1 = p1;
#pragma unroll
        for (int d = 1; d < 64; d <<= 1) {
            sum0 += __shfl_xor(sum0, d);
            sum1 += __shfl_xor(sum1, d);
        }
        float rsel = hsel ? (1.f / sum1) : (1.f / sum0);

        // pass B: 32 edges per outer iter, 8 gathers in flight per lane
        __half2 z = __float2half2_rn(0.f);
        __half2 hacc0 = z, hacc1 = z, hacc2 = z, hacc3 = z;
        for (int k0 = 0; k0 < tot; k0 += 32) {
            uint4 v[8];
            __half2 al2[8];
#pragma unroll
            for (int u = 0; u < 8; u++) {
                int k = k0 + 4 * u + g;
                int ks = k & 63;  // safe wrap; al=0 for k>=tot
                int sn = __shfl(c, ks);
                float pa = __shfl(p0, ks);
                float pb = __shfl(p1, ks);
                float alf = (k < tot) ? (hsel ? pb : pa) * rsel : 0.f;
                al2[u] = __float2half2_rn(alf);
                v[u] = *reinterpret_cast<const uint4*>(h1h + (size_t)sn * 128 + 8 * chq);
            }
#pragma unroll
            for (int u = 0; u < 8; u++) {
                hacc0 = __hfma2(al2[u], u2h(v[u].x), hacc0);
                hacc1 = __hfma2(al2[u], u2h(v[u].y), hacc1);
                hacc2 = __hfma2(al2[u], u2h(v[u].z), hacc2);
                hacc3 = __hfma2(al2[u], u2h(v[u].w), hacc3);
            }
        }
        f[0] = __low2float(hacc0); f[1] = __high2float(hacc0);
        f[2] = __low2float(hacc1); f[3] = __high2float(hacc1);
        f[4] = __low2float(hacc2); f[5] = __high2float(hacc2);
        f[6] = __low2float(hacc3); f[7] = __high2float(hacc3);
    } else {
        float sum0 = 0.f, sum1 = 0.f;
        for (int l = lane; l < tot; l += 64) {
            int c = (l == 0) ? node : ell_resolve(ell, pre, node, l);
            float4 a = attv[c];
            float e0 = a.x + ad0; e0 = e0 > 0.f ? e0 : NEG_SLOPE * e0;
            float e1 = a.y + ad1; e1 = e1 > 0.f ? e1 : NEG_SLOPE * e1;
            sum0 += __expf(e0); sum1 += __expf(e1);
        }
#pragma unroll
        for (int d = 1; d < 64; d <<= 1) {
            sum0 += __shfl_xor(sum0, d);
            sum1 += __shfl_xor(sum1, d);
        }
        float rsel = hsel ? (1.f / sum1) : (1.f / sum0);
        float acc[8];
#pragma unroll
        for (int i = 0; i < 8; i++) acc[i] = 0.f;
        for (int j = 0; j < tot; j += 4) {
            int l = j + g;
            bool valid = (l < tot);
            int lc = valid ? l : 0;
            int sn = (lc == 0) ? node : ell_resolve(ell, pre, node, lc);
            float4 a = attv[sn];
            float e0 = a.x + ad0; e0 = e0 > 0.f ? e0 : NEG_SLOPE * e0;
            float e1 = a.y + ad1; e1 = e1 > 0.f ? e1 : NEG_SLOPE * e1;
            float pp = hsel ? __expf(e1) : __expf(e0);
            float al = valid ? pp * rsel : 0.f;
            uint4 v = *reinterpret_cast<const uint4*>(h1h + (size_t)sn * 128 + 8 * chq);
            fmamix8(v, al, acc);
        }
#pragma unroll
        for (int i = 0; i < 8; i++) f[i] = acc[i];
    }

    // full reduction -> every lane holds its chq-channel sums
#pragma unroll
    for (int i = 0; i < 8; i++) {
        f[i] += __shfl_xor(f[i], 16);
        f[i] += __shfl_xor(f[i], 32);
    }

    // bias + ELU (ALL lanes; lane L holds channels 8*(L&15)..+7)
    const float4* bv = (const float4*)bias;
    float4 bA = bv[2 * chq], bB = bv[2 * chq + 1];
    float o[8];
    o[0] = f[0] + bA.x; o[1] = f[1] + bA.y;
    o[2] = f[2] + bA.z; o[3] = f[3] + bA.w;
    o[4] = f[4] + bB.x; o[5] = f[5] + bB.y;
    o[6] = f[6] + bB.z; o[7] = f[7] + bB.w;
#pragma unroll
    for (int i = 0; i < 8; i++) o[i] = o[i] > 0.f ? o[i] : (__expf(o[i]) - 1.f);  // ELU

    // fused GEMM2: lane c computes h2[node][c] = sum_k x2[k] * W2[k][c]
    float h2c = 0.f;
    const uint4* wcol = reinterpret_cast<const uint4*>(Wt2h + (size_t)lane * 128);
#pragma unroll
    for (int h = 0; h < 2; h++) {
        uint4 wv[8];
#pragma unroll
        for (int m = 0; m < 8; m++) wv[m] = wcol[h * 8 + m];
#pragma unroll
        for (int m = 0; m < 8; m++) {
            int q = h * 8 + m;  // holder lane for channels 8q..8q+7
            float xk[8];
#pragma unroll
            for (int j = 0; j < 8; j++)
                xk[j] = __int_as_float(RDLANE(__float_as_int(o[j]), q));
            __half2 w01 = u2h(wv[m].x), w23 = u2h(wv[m].y);
            __half2 w45 = u2h(wv[m].z), w67 = u2h(wv[m].w);
            h2c = fmaf(xk[0], __low2float(w01), h2c);
            h2c = fmaf(xk[1], __high2float(w01), h2c);
            h2c = fmaf(xk[2], __low2float(w23), h2c);
            h2c = fmaf(xk[3], __high2float(w23), h2c);
            h2c = fmaf(xk[4], __low2float(w45), h2c);
            h2c = fmaf(xk[5], __high2float(w45), h2c);
            h2c = fmaf(xk[6], __low2float(w67), h2c);
            h2c = fmaf(xk[7], __high2float(w67), h2c);
        }
    }
    h2h[(size_t)node * 64 + lane] = __float2half(h2c);

    // fused att2 dots
    float s2 = h2c * as2[lane];
    float d2 = h2c * ad2[lane];
#pragma unroll
    for (int off = 1; off < 64; off <<= 1) {
        s2 += __shfl_xor(s2, off);
        d2 += __shfl_xor(d2, off);
    }
    if (lane == 0) ((float2*)att2)[node] = make_float2(s2, d2);
}

// ---------------------------------------------------------------------------
// aggr2: one 64-lane wave per dst node, 1 head x 64 ch.
// Pass B: 32 edges/outer iter (MLP=4/lane), fp16 hfma2; fp32 out.
// ---------------------------------------------------------------------------
__global__ __launch_bounds__(256) void k_aggr2(const int* __restrict__ cur,
                                               const unsigned short* __restrict__ ell,
                                               const float* __restrict__ att,
                                               const __half* __restrict__ h2h,
                                               const float* __restrict__ bias,
                                               float* __restrict__ out, int n) {
    int wid = threadIdx.x >> 6, lane = threadIdx.x & 63;
    int node = blockIdx.x * 4 + wid;
    if (node >= n) return;

    int cnt = 0;
    if (lane < NPART) cnt = cur[node * NPART + lane];
    int pre[NPART];
    int tot = 1;
#pragma unroll
    for (int p = 0; p < NPART; p++) {
        int cc = __shfl(cnt, p);
        cc = cc < WSLOT ? cc : WSLOT;
        pre[p] = tot;
        tot += cc;
    }

    const float2* attv = (const float2*)att;
    float adn = attv[node].y;
    int chq = lane & 7;
    int g = lane >> 3;

    float f[8];

    if (tot <= 64) {
        int c = node;
        float p = 0.f;
        if (lane < tot) {
            if (lane > 0) c = ell_resolve(ell, pre, node, lane);
            float e = attv[c].x + adn;
            e = e > 0.f ? e : NEG_SLOPE * e;
            p = __expf(e);
        }
        float sum = p;
#pragma unroll
        for (int d = 1; d < 64; d <<= 1) sum += __shfl_xor(sum, d);
        float r = 1.f / sum;

        __half2 z = __float2half2_rn(0.f);
        __half2 hacc0 = z, hacc1 = z, hacc2 = z, hacc3 = z;
        for (int k0 = 0; k0 < tot; k0 += 32) {
            uint4 v[4];
            __half2 al2[4];
#pragma unroll
            for (int u = 0; u < 4; u++) {
                int k = k0 + 8 * u + g;
                int ks = k & 63;
                int sn = __shfl(c, ks);
                float pk = __shfl(p, ks);
                float alf = (k < tot) ? pk * r : 0.f;
                al2[u] = __float2half2_rn(alf);
                v[u] = *reinterpret_cast<const uint4*>(h2h + (size_t)sn * 64 + 8 * chq);
            }
#pragma unroll
            for (int u = 0; u < 4; u++) {
                hacc0 = __hfma2(al2[u], u2h(v[u].x), hacc0);
                hacc1 = __hfma2(al2[u], u2h(v[u].y), hacc1);
                hacc2 = __hfma2(al2[u], u2h(v[u].z), hacc2);
                hacc3 = __hfma2(al2[u], u2h(v[u].w), hacc3);
            }
        }
        f[0] = __low2float(hacc0); f[1] = __high2float(hacc0);
        f[2] = __low2float(hacc1); f[3] = __high2float(hacc1);
        f[4] = __low2float(hacc2); f[5] = __high2float(hacc2);
        f[6] = __low2float(hacc3); f[7] = __high2float(hacc3);
    } else {
        float sum = 0.f;
        for (int l = lane; l < tot; l += 64) {
            int c = (l == 0) ? node : ell_resolve(ell, pre, node, l);
            float e = attv[c].x + adn;
            e = e > 0.f ? e : NEG_SLOPE * e;
            sum += __expf(e);
        }
#pragma unroll
        for (int d = 1; d < 64; d <<= 1) sum += __shfl_xor(sum, d);
        float r = 1.f / sum;
        float acc[8];
#pragma unroll
        for (int i = 0; i < 8; i++) acc[i] = 0.f;
        for (int j = 0; j < tot; j += 8) {
            int l = j + g;
            bool valid = (l < tot);
            int lc = valid ? l : 0;
            int sn = (lc == 0) ? node : ell_resolve(ell, pre, node, lc);
            float e = attv[sn].x + adn;
            e = e > 0.f ? e : NEG_SLOPE * e;
            float al = valid ? __expf(e) * r : 0.f;
            uint4 v = *reinterpret_cast<const uint4*>(h2h + (size_t)sn * 64 + 8 * chq);
            fmamix8(v, al, acc);
        }
#pragma unroll
        for (int i = 0; i < 8; i++) f[i] = acc[i];
    }

#pragma unroll
    for (int i = 0; i < 8; i++) {
        f[i] += __shfl_xor(f[i], 8);
        f[i] += __shfl_xor(f[i], 16);
        f[i] += __shfl_xor(f[i], 32);
    }
    if (lane < 8) {
        const float4* bv = (const float4*)bias;
        float4 bA = bv[2 * chq], bB = bv[2 * chq + 1];
        float4* ov = (float4*)(out + (size_t)node * 64 + 8 * chq);
        ov[0] = make_float4(f[0] + bA.x, f[1] + bA.y, f[2] + bA.z, f[3] + bA.w);
        ov[1] = make_float4(f[4] + bB.x, f[5] + bB.y, f[6] + bB.z, f[7] + bB.w);
    }
}

// ---------------------------------------------------------------------------
// Launch
// ---------------------------------------------------------------------------
extern "C" void kernel_launch(void* const* d_in, const int* in_sizes, int n_in,
                              void* d_out, int out_size, void* d_ws, size_t ws_size,
                              hipStream_t stream) {
    const float* x    = (const float*)d_in[0];
    const int*   ei   = (const int*)d_in[1];
    const float* W1   = (const float*)d_in[2];
    const float* asr1 = (const float*)d_in[3];
    const float* adt1 = (const float*)d_in[4];
    const float* b1   = (const float*)d_in[5];
    const float* W2   = (const float*)d_in[6];
    const float* asr2 = (const float*)d_in[7];
    const float* adt2 = (const float*)d_in[8];
    const float* b2   = (const float*)d_in[9];
    float* out = (float*)d_out;

    const int N = in_sizes[0] / 128;
    const int E = in_sizes[1] / 2;
    const int* srcI = ei;
    const int* dstI = ei + E;

    char* p = (char*)d_ws;
    auto alloc = [&](size_t b) -> void* {
        void* r = (void*)p;
        p += ((b + 255) / 256) * 256;
        return r;
    };
    int* cur = (int*)alloc(sizeof(int) * (size_t)NPART * N);                       // 1.6 MB
    unsigned short* ell = (unsigned short*)alloc(sizeof(unsigned short) *
                                                 (size_t)NPART * N * WSLOT);       // 12.8 MB
    __half* h1h = (__half*)alloc(sizeof(__half) * (size_t)N * 128);                // 12.8 MB
    float* att1 = (float*)alloc(sizeof(float) * (size_t)N * 4);
    __half* h2h = (__half*)alloc(sizeof(__half) * (size_t)N * 64);
    float* att2 = (float*)alloc(sizeof(float) * (size_t)N * 2);
    __half* Wt2h = (__half*)alloc(sizeof(__half) * 64 * 128);                      // 16 KB

    int S = (E + 1023) / 1024;          // scatter blocks (4 edges/thread)
    int G = (N + 31) / 32;              // gemm1 blocks
    int nbNode4 = (N + 3) / 4;          // 1 node per 64-lane wave

    // cur zeroed async (capture-safe)
    hipMemsetAsync(cur, 0, sizeof(int) * (size_t)NPART * N, stream);

    // W2 transpose to fp16 [c][k] (16 KB, built once; cache-resident after)
    k_wt2<<<32, 256, 0, stream>>>(W2, Wt2h);

    // Fused: scatter (1/3 of blocks, interleaved) + GEMM1/att1 (2/3)
    k_fused1<<<S + G, 256, 0, stream>>>(srcI, dstI, E, S, G, cur, ell,
                                        x, W1, asr1, adt1, h1h, att1, N);

    // Layer-1 aggregation + bias/ELU + fused GEMM2 + att2 (x2 never hits memory)
    k_aggr1g2<<<nbNode4, 256, 0, stream>>>(cur, ell, att1, h1h, b1, Wt2h,
                                           asr2, adt2, h2h, att2, N);

    // Layer-2 aggregation -> out
    k_aggr2<<<nbNode4, 256, 0, stream>>>(cur, ell, att2, h2h, b2, out, N);
}

// Round 13
// 142.276 us; speedup vs baseline: 1.3811x; 1.3811x over previous
//
#include <hip/hip_runtime.h>
#include <hip/hip_fp16.h>
#include <math.h>

constexpr float NEG_SLOPE = 0.2f;
constexpr int NPART = 8;   // partitions (blockIdx & 7 proxy)
constexpr int WSLOT = 16;  // slots per (node,partition)

// ---------------------------------------------------------------------------
// helpers
// ---------------------------------------------------------------------------
__device__ inline __half2 u2h(unsigned int u) { return *reinterpret_cast<__half2*>(&u); }
__device__ inline unsigned int h2u(__half2 h) { return *reinterpret_cast<unsigned int*>(&h); }

__device__ inline void fmamix8(uint4 v, float al, float* acc) {
    float2 f0 = __half22float2(u2h(v.x)), f1 = __half22float2(u2h(v.y));
    float2 f2 = __half22float2(u2h(v.z)), f3 = __half22float2(u2h(v.w));
    acc[0] = fmaf(al, f0.x, acc[0]); acc[1] = fmaf(al, f0.y, acc[1]);
    acc[2] = fmaf(al, f1.x, acc[2]); acc[3] = fmaf(al, f1.y, acc[3]);
    acc[4] = fmaf(al, f2.x, acc[4]); acc[5] = fmaf(al, f2.y, acc[5]);
    acc[6] = fmaf(al, f3.x, acc[6]); acc[7] = fmaf(al, f3.y, acc[7]);
}

// resolve virtual list index l (>=1) -> source node id; node-major ELL:
// ell[(node*NPART + p)*WSLOT + slot] -- all partitions of a node in 256 B.
__device__ inline int ell_resolve(const unsigned short* __restrict__ ell,
                                  const int* pre, int node, int l) {
    int p = 0;
#pragma unroll
    for (int t = 1; t < NPART; t++)
        if (l >= pre[t]) p = t;
    int slot = l - pre[p];
    return (int)ell[((size_t)node * NPART + p) * WSLOT + slot];
}

// ---------------------------------------------------------------------------
// FUSED: scatter (ELL build) interleaved 1:2 with GEMM1+att1.
// GEMM: W staged in two 64-row fp16 halves -> 32 KB LDS -> 5 blocks/CU.
// ---------------------------------------------------------------------------
__global__ __launch_bounds__(256) void k_fused1(
    const int* __restrict__ src, const int* __restrict__ dst, int e, int S, int G,
    int* __restrict__ cur, unsigned short* __restrict__ ell,
    const float* __restrict__ x, const float* __restrict__ W,
    const float* __restrict__ a_src, const float* __restrict__ a_dst,
    __half* __restrict__ h1h, float* __restrict__ att, int n) {
    __shared__ float xs[32 * 128];    // 16 KB
    __shared__ __half wsh[64 * 128];  // 16 KB (half-K W tile)
    int bid = blockIdx.x;
    int t = threadIdx.x;

    int third = bid / 3;
    bool interleave = (2 * S <= G + 2);
    bool isScat = interleave ? ((bid % 3 == 0) && (third < S)) : (bid < S);
    if (isScat) {
        int sid = interleave ? third : bid;
        int p = bid & (NPART - 1);
        int i0 = (sid * 256 + t) * 4;
        if (i0 + 3 < e) {
            int4 d4 = *reinterpret_cast<const int4*>(dst + i0);
            int4 s4 = *reinterpret_cast<const int4*>(src + i0);
            int a0 = atomicAdd(&cur[d4.x * NPART + p], 1);
            int a1 = atomicAdd(&cur[d4.y * NPART + p], 1);
            int a2 = atomicAdd(&cur[d4.z * NPART + p], 1);
            int a3 = atomicAdd(&cur[d4.w * NPART + p], 1);
            if (a0 < WSLOT) ell[((size_t)d4.x * NPART + p) * WSLOT + a0] = (unsigned short)s4.x;
            if (a1 < WSLOT) ell[((size_t)d4.y * NPART + p) * WSLOT + a1] = (unsigned short)s4.y;
            if (a2 < WSLOT) ell[((size_t)d4.z * NPART + p) * WSLOT + a2] = (unsigned short)s4.z;
            if (a3 < WSLOT) ell[((size_t)d4.w * NPART + p) * WSLOT + a3] = (unsigned short)s4.w;
        } else {
            for (int i = i0; i < e; i++) {
                int d = dst[i];
                int slot = atomicAdd(&cur[d * NPART + p], 1);
                if (slot < WSLOT) ell[((size_t)d * NPART + p) * WSLOT + slot] = (unsigned short)src[i];
            }
        }
        return;
    }
    int gid = interleave ? (bid - min(S, (bid + 2) / 3)) : (bid - S);
    if (gid >= G) return;

    // ---- GEMM1 (32 rows x 128 cols), W fp16 half-K staged ----
    int row0 = gid * 32;
    const float4* xv = (const float4*)x;
    float4* xsv = (float4*)xs;
#pragma unroll
    for (int ii = 0; ii < 4; ii++) {
        int i = t + 256 * ii;
        int r = i >> 5, c4 = i & 31;
        int gr = row0 + r;
        float4 v = (gr < n) ? xv[(size_t)gr * 32 + c4] : make_float4(0.f, 0.f, 0.f, 0.f);
        xsv[i] = v;
    }

    int tc = t & 31;   // cols 4tc..4tc+3
    int tr = t >> 5;   // rows 4tr..4tr+3
    float acc[4][4];
#pragma unroll
    for (int i = 0; i < 4; i++)
#pragma unroll
        for (int j = 0; j < 4; j++) acc[i][j] = 0.f;

    const float4* Wv = (const float4*)W;
    uint2* wsv = (uint2*)wsh;
    const uint2* wsv2 = (const uint2*)wsh;
#pragma unroll
    for (int kh = 0; kh < 2; kh++) {
        __syncthreads();  // first iter: covers x staging; later: wsh reuse
        // stage W rows kh*64..kh*64+63 (fp32 -> fp16)
#pragma unroll
        for (int ii = 0; ii < 8; ii++) {
            int i = t + 256 * ii;  // 0..2047 float4s within this half
            float4 w = Wv[kh * 2048 + i];
            __half2 a = __floats2half2_rn(w.x, w.y);
            __half2 b = __floats2half2_rn(w.z, w.w);
            uint2 o; o.x = h2u(a); o.y = h2u(b);
            wsv[i] = o;
        }
        __syncthreads();
        for (int kk = 0; kk < 64; kk++) {
            uint2 wu = wsv2[kk * 32 + tc];
            float2 wA = __half22float2(u2h(wu.x));
            float2 wB = __half22float2(u2h(wu.y));
#pragma unroll
            for (int i = 0; i < 4; i++) {
                float xvv = xs[(tr * 4 + i) * 128 + kh * 64 + kk];
                acc[i][0] = fmaf(xvv, wA.x, acc[i][0]);
                acc[i][1] = fmaf(xvv, wA.y, acc[i][1]);
                acc[i][2] = fmaf(xvv, wB.x, acc[i][2]);
                acc[i][3] = fmaf(xvv, wB.y, acc[i][3]);
            }
        }
    }

#pragma unroll
    for (int i = 0; i < 4; i++) {
        int gr = row0 + tr * 4 + i;
        if (gr < n) {
            __half2 p01 = __floats2half2_rn(acc[i][0], acc[i][1]);
            __half2 p23 = __floats2half2_rn(acc[i][2], acc[i][3]);
            uint2 o; o.x = h2u(p01); o.y = h2u(p23);
            *reinterpret_cast<uint2*>(h1h + (size_t)gr * 128 + 4 * tc) = o;
        }
    }
    // fused att dots
    const float4* asv = (const float4*)a_src;  // [32] float4 = 128 ch
    const float4* adv = (const float4*)a_dst;
    float4 as4 = asv[tc], ad4 = adv[tc];
    int lane = t & 63;
#pragma unroll
    for (int i = 0; i < 4; i++) {
        float s = acc[i][0] * as4.x + acc[i][1] * as4.y + acc[i][2] * as4.z + acc[i][3] * as4.w;
        float d = acc[i][0] * ad4.x + acc[i][1] * ad4.y + acc[i][2] * ad4.z + acc[i][3] * ad4.w;
#pragma unroll
        for (int o = 1; o < 16; o <<= 1) {
            s += __shfl_xor(s, o);
            d += __shfl_xor(d, o);
        }
        float s1 = __shfl(s, (lane & 32) + 16);
        float d1 = __shfl(d, (lane & 32) + 16);
        int gr = row0 + tr * 4 + i;
        if ((lane & 31) == 0 && gr < n) {
            ((float4*)att)[gr] = make_float4(s, s1, d, d1);
        }
    }
}

// ---------------------------------------------------------------------------
// GEMM2: h2h[N,64](fp16) = x2h[N,128](fp16) @ W2[128,64]; fused att2 dots.
// W staged fp16 (16 KB); total LDS 32 KB -> 5 blocks/CU.
// ---------------------------------------------------------------------------
__global__ __launch_bounds__(256) void k_gemm2(const __half* __restrict__ x2h,
                                               const float* __restrict__ W,
                                               const float* __restrict__ a_src,
                                               const float* __restrict__ a_dst,
                                               __half* __restrict__ h2h,
                                               float* __restrict__ att, int n) {
    __shared__ float xs[32 * 128];   // 16 KB
    __shared__ __half wsh[128 * 64]; // 16 KB
    int t = threadIdx.x;
    const float4* Wv = (const float4*)W;
    uint2* wsv = (uint2*)wsh;
#pragma unroll
    for (int i = 0; i < 8; i++) {
        float4 w = Wv[t + 256 * i];
        __half2 a = __floats2half2_rn(w.x, w.y);
        __half2 b = __floats2half2_rn(w.z, w.w);
        uint2 o; o.x = h2u(a); o.y = h2u(b);
        wsv[t + 256 * i] = o;
    }
    int row0 = blockIdx.x * 32;
    const uint2* xv = (const uint2*)x2h;
    float4* xsv = (float4*)xs;
#pragma unroll
    for (int ii = 0; ii < 4; ii++) {
        int i = t + 256 * ii;
        int r = i >> 5, c4 = i & 31;
        int gr = row0 + r;
        uint2 u = (gr < n) ? xv[(size_t)gr * 32 + c4] : make_uint2(0u, 0u);
        float2 lo = __half22float2(u2h(u.x)), hi = __half22float2(u2h(u.y));
        xsv[i] = make_float4(lo.x, lo.y, hi.x, hi.y);
    }
    __syncthreads();
    int tc = t & 15;  // cols 4tc..4tc+3
    int tr = t >> 4;  // rows 2tr..2tr+1
    float acc[2][4];
#pragma unroll
    for (int i = 0; i < 2; i++)
#pragma unroll
        for (int j = 0; j < 4; j++) acc[i][j] = 0.f;
    const uint2* wsv2 = (const uint2*)wsh;
    for (int k = 0; k < 128; k++) {
        uint2 wu = wsv2[k * 16 + tc];
        float2 wA = __half22float2(u2h(wu.x));
        float2 wB = __half22float2(u2h(wu.y));
#pragma unroll
        for (int i = 0; i < 2; i++) {
            float xvv = xs[(tr * 2 + i) * 128 + k];
            acc[i][0] = fmaf(xvv, wA.x, acc[i][0]);
            acc[i][1] = fmaf(xvv, wA.y, acc[i][1]);
            acc[i][2] = fmaf(xvv, wB.x, acc[i][2]);
            acc[i][3] = fmaf(xvv, wB.y, acc[i][3]);
        }
    }
#pragma unroll
    for (int i = 0; i < 2; i++) {
        int gr = row0 + tr * 2 + i;
        if (gr < n) {
            __half2 p01 = __floats2half2_rn(acc[i][0], acc[i][1]);
            __half2 p23 = __floats2half2_rn(acc[i][2], acc[i][3]);
            uint2 o; o.x = h2u(p01); o.y = h2u(p23);
            *reinterpret_cast<uint2*>(h2h + (size_t)gr * 64 + 4 * tc) = o;
        }
    }
    const float4* asv = (const float4*)a_src;  // [16] float4
    const float4* adv = (const float4*)a_dst;
    float4 as4 = asv[tc], ad4 = adv[tc];
#pragma unroll
    for (int i = 0; i < 2; i++) {
        float s = acc[i][0] * as4.x + acc[i][1] * as4.y + acc[i][2] * as4.z + acc[i][3] * as4.w;
        float d = acc[i][0] * ad4.x + acc[i][1] * ad4.y + acc[i][2] * ad4.z + acc[i][3] * ad4.w;
#pragma unroll
        for (int o = 1; o < 16; o <<= 1) {
            s += __shfl_xor(s, o);
            d += __shfl_xor(d, o);
        }
        int gr = row0 + tr * 2 + i;
        if (tc == 0 && gr < n) {
            ((float2*)att)[gr] = make_float2(s, d);
        }
    }
}

// ---------------------------------------------------------------------------
// aggr1: one 64-lane wave per dst node, 2 heads x 64 ch.
// Pass B: 32 edges/outer iter (MLP=8/lane), fp16 hfma2. Output x2 fp16.
// ---------------------------------------------------------------------------
__global__ __launch_bounds__(256) void k_aggr1(const int* __restrict__ cur,
                                               const unsigned short* __restrict__ ell,
                                               const float* __restrict__ att,
                                               const __half* __restrict__ h1h,
                                               const float* __restrict__ bias,
                                               __half* __restrict__ x2h, int n) {
    int wid = threadIdx.x >> 6, lane = threadIdx.x & 63;
    int node = blockIdx.x * 4 + wid;
    if (node >= n) return;

    int cnt = 0;
    if (lane < NPART) cnt = cur[node * NPART + lane];  // coalesced 32 B
    int pre[NPART];
    int tot = 1;  // implicit self-loop at l=0
#pragma unroll
    for (int p = 0; p < NPART; p++) {
        int cc = __shfl(cnt, p);
        cc = cc < WSLOT ? cc : WSLOT;
        pre[p] = tot;
        tot += cc;
    }

    const float4* attv = (const float4*)att;
    float4 an = attv[node];
    float ad0 = an.z, ad1 = an.w;

    int chq = lane & 15;
    int g = lane >> 4;
    bool hsel = (chq >= 8);

    float f[8];

    if (tot <= 64) {
        int c = node;
        float p0 = 0.f, p1 = 0.f;
        if (lane < tot) {
            if (lane > 0) c = ell_resolve(ell, pre, node, lane);
            float4 a = attv[c];
            float e0 = a.x + ad0; e0 = e0 > 0.f ? e0 : NEG_SLOPE * e0;
            float e1 = a.y + ad1; e1 = e1 > 0.f ? e1 : NEG_SLOPE * e1;
            p0 = __expf(e0); p1 = __expf(e1);
        }
        float sum0 = p0, sum1 = p1;
#pragma unroll
        for (int d = 1; d < 64; d <<= 1) {
            sum0 += __shfl_xor(sum0, d);
            sum1 += __shfl_xor(sum1, d);
        }
        float rsel = hsel ? (1.f / sum1) : (1.f / sum0);

        // pass B: 32 edges per outer iter, 8 gathers in flight per lane
        __half2 z = __float2half2_rn(0.f);
        __half2 hacc0 = z, hacc1 = z, hacc2 = z, hacc3 = z;
        for (int k0 = 0; k0 < tot; k0 += 32) {
            uint4 v[8];
            __half2 al2[8];
#pragma unroll
            for (int u = 0; u < 8; u++) {
                int k = k0 + 4 * u + g;
                int ks = k & 63;  // safe wrap; al=0 for k>=tot
                int sn = __shfl(c, ks);
                float pa = __shfl(p0, ks);
                float pb = __shfl(p1, ks);
                float alf = (k < tot) ? (hsel ? pb : pa) * rsel : 0.f;
                al2[u] = __float2half2_rn(alf);
                v[u] = *reinterpret_cast<const uint4*>(h1h + (size_t)sn * 128 + 8 * chq);
            }
#pragma unroll
            for (int u = 0; u < 8; u++) {
                hacc0 = __hfma2(al2[u], u2h(v[u].x), hacc0);
                hacc1 = __hfma2(al2[u], u2h(v[u].y), hacc1);
                hacc2 = __hfma2(al2[u], u2h(v[u].z), hacc2);
                hacc3 = __hfma2(al2[u], u2h(v[u].w), hacc3);
            }
        }
        f[0] = __low2float(hacc0); f[1] = __high2float(hacc0);
        f[2] = __low2float(hacc1); f[3] = __high2float(hacc1);
        f[4] = __low2float(hacc2); f[5] = __high2float(hacc2);
        f[6] = __low2float(hacc3); f[7] = __high2float(hacc3);
    } else {
        float sum0 = 0.f, sum1 = 0.f;
        for (int l = lane; l < tot; l += 64) {
            int c = (l == 0) ? node : ell_resolve(ell, pre, node, l);
            float4 a = attv[c];
            float e0 = a.x + ad0; e0 = e0 > 0.f ? e0 : NEG_SLOPE * e0;
            float e1 = a.y + ad1; e1 = e1 > 0.f ? e1 : NEG_SLOPE * e1;
            sum0 += __expf(e0); sum1 += __expf(e1);
        }
#pragma unroll
        for (int d = 1; d < 64; d <<= 1) {
            sum0 += __shfl_xor(sum0, d);
            sum1 += __shfl_xor(sum1, d);
        }
        float rsel = hsel ? (1.f / sum1) : (1.f / sum0);
        float acc[8];
#pragma unroll
        for (int i = 0; i < 8; i++) acc[i] = 0.f;
        for (int j = 0; j < tot; j += 4) {
            int l = j + g;
            bool valid = (l < tot);
            int lc = valid ? l : 0;
            int sn = (lc == 0) ? node : ell_resolve(ell, pre, node, lc);
            float4 a = attv[sn];
            float e0 = a.x + ad0; e0 = e0 > 0.f ? e0 : NEG_SLOPE * e0;
            float e1 = a.y + ad1; e1 = e1 > 0.f ? e1 : NEG_SLOPE * e1;
            float pp = hsel ? __expf(e1) : __expf(e0);
            float al = valid ? pp * rsel : 0.f;
            uint4 v = *reinterpret_cast<const uint4*>(h1h + (size_t)sn * 128 + 8 * chq);
            fmamix8(v, al, acc);
        }
#pragma unroll
        for (int i = 0; i < 8; i++) f[i] = acc[i];
    }

#pragma unroll
    for (int i = 0; i < 8; i++) {
        f[i] += __shfl_xor(f[i], 16);
        f[i] += __shfl_xor(f[i], 32);
    }
    if (lane < 16) {
        const float4* bv = (const float4*)bias;
        float4 bA = bv[2 * chq], bB = bv[2 * chq + 1];
        float o[8];
        o[0] = f[0] + bA.x; o[1] = f[1] + bA.y;
        o[2] = f[2] + bA.z; o[3] = f[3] + bA.w;
        o[4] = f[4] + bB.x; o[5] = f[5] + bB.y;
        o[6] = f[6] + bB.z; o[7] = f[7] + bB.w;
#pragma unroll
        for (int i = 0; i < 8; i++) o[i] = o[i] > 0.f ? o[i] : (__expf(o[i]) - 1.f);  // ELU
        __half2 q01 = __floats2half2_rn(o[0], o[1]);
        __half2 q23 = __floats2half2_rn(o[2], o[3]);
        __half2 q45 = __floats2half2_rn(o[4], o[5]);
        __half2 q67 = __floats2half2_rn(o[6], o[7]);
        uint4 w; w.x = h2u(q01); w.y = h2u(q23); w.z = h2u(q45); w.w = h2u(q67);
        *reinterpret_cast<uint4*>(x2h + (size_t)node * 128 + 8 * chq) = w;
    }
}

// ---------------------------------------------------------------------------
// aggr2: one 64-lane wave per dst node, 1 head x 64 ch.
// Pass B: 32 edges/outer iter (MLP=4/lane), fp16 hfma2; fp32 out.
// ---------------------------------------------------------------------------
__global__ __launch_bounds__(256) void k_aggr2(const int* __restrict__ cur,
                                               const unsigned short* __restrict__ ell,
                                               const float* __restrict__ att,
                                               const __half* __restrict__ h2h,
                                               const float* __restrict__ bias,
                                               float* __restrict__ out, int n) {
    int wid = threadIdx.x >> 6, lane = threadIdx.x & 63;
    int node = blockIdx.x * 4 + wid;
    if (node >= n) return;

    int cnt = 0;
    if (lane < NPART) cnt = cur[node * NPART + lane];
    int pre[NPART];
    int tot = 1;
#pragma unroll
    for (int p = 0; p < NPART; p++) {
        int cc = __shfl(cnt, p);
        cc = cc < WSLOT ? cc : WSLOT;
        pre[p] = tot;
        tot += cc;
    }

    const float2* attv = (const float2*)att;
    float adn = attv[node].y;
    int chq = lane & 7;
    int g = lane >> 3;

    float f[8];

    if (tot <= 64) {
        int c = node;
        float p = 0.f;
        if (lane < tot) {
            if (lane > 0) c = ell_resolve(ell, pre, node, lane);
            float e = attv[c].x + adn;
            e = e > 0.f ? e : NEG_SLOPE * e;
            p = __expf(e);
        }
        float sum = p;
#pragma unroll
        for (int d = 1; d < 64; d <<= 1) sum += __shfl_xor(sum, d);
        float r = 1.f / sum;

        __half2 z = __float2half2_rn(0.f);
        __half2 hacc0 = z, hacc1 = z, hacc2 = z, hacc3 = z;
        for (int k0 = 0; k0 < tot; k0 += 32) {
            uint4 v[4];
            __half2 al2[4];
#pragma unroll
            for (int u = 0; u < 4; u++) {
                int k = k0 + 8 * u + g;
                int ks = k & 63;
                int sn = __shfl(c, ks);
                float pk = __shfl(p, ks);
                float alf = (k < tot) ? pk * r : 0.f;
                al2[u] = __float2half2_rn(alf);
                v[u] = *reinterpret_cast<const uint4*>(h2h + (size_t)sn * 64 + 8 * chq);
            }
#pragma unroll
            for (int u = 0; u < 4; u++) {
                hacc0 = __hfma2(al2[u], u2h(v[u].x), hacc0);
                hacc1 = __hfma2(al2[u], u2h(v[u].y), hacc1);
                hacc2 = __hfma2(al2[u], u2h(v[u].z), hacc2);
                hacc3 = __hfma2(al2[u], u2h(v[u].w), hacc3);
            }
        }
        f[0] = __low2float(hacc0); f[1] = __high2float(hacc0);
        f[2] = __low2float(hacc1); f[3] = __high2float(hacc1);
        f[4] = __low2float(hacc2); f[5] = __high2float(hacc2);
        f[6] = __low2float(hacc3); f[7] = __high2float(hacc3);
    } else {
        float sum = 0.f;
        for (int l = lane; l < tot; l += 64) {
            int c = (l == 0) ? node : ell_resolve(ell, pre, node, l);
            float e = attv[c].x + adn;
            e = e > 0.f ? e : NEG_SLOPE * e;
            sum += __expf(e);
        }
#pragma unroll
        for (int d = 1; d < 64; d <<= 1) sum += __shfl_xor(sum, d);
        float r = 1.f / sum;
        float acc[8];
#pragma unroll
        for (int i = 0; i < 8; i++) acc[i] = 0.f;
        for (int j = 0; j < tot; j += 8) {
            int l = j + g;
            bool valid = (l < tot);
            int lc = valid ? l : 0;
            int sn = (lc == 0) ? node : ell_resolve(ell, pre, node, lc);
            float e = attv[sn].x + adn;
            e = e > 0.f ? e : NEG_SLOPE * e;
            float al = valid ? __expf(e) * r : 0.f;
            uint4 v = *reinterpret_cast<const uint4*>(h2h + (size_t)sn * 64 + 8 * chq);
            fmamix8(v, al, acc);
        }
#pragma unroll
        for (int i = 0; i < 8; i++) f[i] = acc[i];
    }

#pragma unroll
    for (int i = 0; i < 8; i++) {
        f[i] += __shfl_xor(f[i], 8);
        f[i] += __shfl_xor(f[i], 16);
        f[i] += __shfl_xor(f[i], 32);
    }
    if (lane < 8) {
        const float4* bv = (const float4*)bias;
        float4 bA = bv[2 * chq], bB = bv[2 * chq + 1];
        float4* ov = (float4*)(out + (size_t)node * 64 + 8 * chq);
        ov[0] = make_float4(f[0] + bA.x, f[1] + bA.y, f[2] + bA.z, f[3] + bA.w);
        ov[1] = make_float4(f[4] + bB.x, f[5] + bB.y, f[6] + bB.z, f[7] + bB.w);
    }
}

// ---------------------------------------------------------------------------
// Launch
// ---------------------------------------------------------------------------
extern "C" void kernel_launch(void* const* d_in, const int* in_sizes, int n_in,
                              void* d_out, int out_size, void* d_ws, size_t ws_size,
                              hipStream_t stream) {
    const float* x    = (const float*)d_in[0];
    const int*   ei   = (const int*)d_in[1];
    const float* W1   = (const float*)d_in[2];
    const float* asr1 = (const float*)d_in[3];
    const float* adt1 = (const float*)d_in[4];
    const float* b1   = (const float*)d_in[5];
    const float* W2   = (const float*)d_in[6];
    const float* asr2 = (const float*)d_in[7];
    const float* adt2 = (const float*)d_in[8];
    const float* b2   = (const float*)d_in[9];
    float* out = (float*)d_out;

    const int N = in_sizes[0] / 128;
    const int E = in_sizes[1] / 2;
    const int* srcI = ei;
    const int* dstI = ei + E;

    char* p = (char*)d_ws;
    auto alloc = [&](size_t b) -> void* {
        void* r = (void*)p;
        p += ((b + 255) / 256) * 256;
        return r;
    };
    int* cur = (int*)alloc(sizeof(int) * (size_t)NPART * N);                       // 1.6 MB
    unsigned short* ell = (unsigned short*)alloc(sizeof(unsigned short) *
                                                 (size_t)NPART * N * WSLOT);       // 12.8 MB
    __half* h1h = (__half*)alloc(sizeof(__half) * (size_t)N * 128);                // 12.8 MB
    float* att1 = (float*)alloc(sizeof(float) * (size_t)N * 4);
    __half* x2h = (__half*)alloc(sizeof(__half) * (size_t)N * 128);                // 12.8 MB
    __half* h2h = (__half*)alloc(sizeof(__half) * (size_t)N * 64);
    float* att2 = (float*)alloc(sizeof(float) * (size_t)N * 2);

    int S = (E + 1023) / 1024;          // scatter blocks (4 edges/thread)
    int G = (N + 31) / 32;              // gemm1 blocks
    int nbNode4 = (N + 3) / 4;          // 1 node per 64-lane wave
    int nbRow32 = (N + 31) / 32;

    // cur zeroed async (capture-safe)
    hipMemsetAsync(cur, 0, sizeof(int) * (size_t)NPART * N, stream);

    // Fused: scatter (1/3 of blocks, interleaved) + GEMM1/att1 (2/3)
    k_fused1<<<S + G, 256, 0, stream>>>(srcI, dstI, E, S, G, cur, ell,
                                        x, W1, asr1, adt1, h1h, att1, N);

    // Layer 1 aggregation -> x2 (fp16)
    k_aggr1<<<nbNode4, 256, 0, stream>>>(cur, ell, att1, h1h, b1, x2h, N);

    // Layer 2
    k_gemm2<<<nbRow32, 256, 0, stream>>>(x2h, W2, asr2, adt2, h2h, att2, N);
    k_aggr2<<<nbNode4, 256, 0, stream>>>(cur, ell, att2, h2h, b2, out, N);
}